// Round 11
// baseline (490.811 us; speedup 1.0000x reference)
//
#include <hip/hip_runtime.h>
#include <hip/hip_fp16.h>

// LSTM: B=256, T=1024, I=64, H=25 (4H=100), O=64. fp32 in/out.
//
// R11 theory: R10's counters close the case: VALUBusy 23% (wave0's SIMD
//   ~40-50% issue) + all memory restructures neutral + chain-shortening
//   neutral -> the recurrence is LATENCY-bound on its dependency chain
//   (~30 dependent ops x ~11cy real latency = ~350cy stall/step).
//   Fix: overlap TWO independent chains per wave. Recurrent weights are
//   batch-invariant, so batch #2 costs only ~36 VGPRs. Each block now
//   runs 2 batches; wave0 interleaves step t of A and B (chains pipeline
//   through the VALU); grid = 128 blocks. Wave2's 16-row MFMA A-fragment
//   maps exactly to 2 batches x 8 steps (CH back to 8, no wasted rows).
//   Wave1 (mostly idle before) does both batches' FC + stores.
// Structure (validated R9/R10): ONE kernel, 3 waves/block:
//   wave0 = recurrence, wave1 = FC + out, wave2 = gate producer (MFMA).
// Carried: gate split across wave halves, exp2 scale folding, (i,g)/(f,o)
//   layout, xswap via permlane32_swap returning b (validated R4), raw
//   s_barrier + lgkmcnt-only drain, __syncthreads one-time handoffs,
//   R10 algebraic forms (swap raw rB; h = fma(2Og, r2, -Og)).

#define Bn 256
#define Tn 1024
#define In 64
#define Hn 25
#define Gn 100
#define On 64
#define CH 8               // steps per chunk PER BATCH
#define NCH (Tn / CH)      // 128 chunks

#define SCL_S -1.44269504089f   // -log2(e)   : sigmoid gates (i,f,o)
#define SCL_T -2.88539008178f   // -2*log2(e) : tanh gate (g)

typedef __attribute__((ext_vector_type(8))) short short8;
typedef __attribute__((ext_vector_type(4))) float f32x4;
typedef __attribute__((ext_vector_type(4))) int i32x4;

__device__ __forceinline__ float frcp(float x) { return __builtin_amdgcn_rcpf(x); }
__device__ __forceinline__ float ex2(float x) {
    float r;
    asm("v_exp_f32 %0, %1\n\ts_nop 1" : "=v"(r) : "v"(x));
    return r;
}
__device__ __forceinline__ float bcast(float v, int lane) {
    return __int_as_float(__builtin_amdgcn_readlane(__float_as_int(v), lane));
}
__device__ __forceinline__ float xswap(float x) {
    // returned b's LOW lanes hold the high-half value (validated R4..R10).
    float a = x, b = x;
    asm("s_nop 0\n\tv_permlane32_swap_b32 %0, %1\n\ts_nop 0"
        : "+v"(a), "+v"(b));
    return b;
}
__device__ __forceinline__ unsigned short f2bf(float f) {   // RNE fp32->bf16
    unsigned u = __float_as_uint(f);
    return (unsigned short)((u + 0x7FFFu + ((u >> 16) & 1u)) >> 16);
}
__device__ __forceinline__ int pk2(float lo, float hi) {
    return (int)(((unsigned)f2bf(hi) << 16) | f2bf(lo));
}

// gate column map: n<50: unit n>>1, gate i (even) / g (odd);
//                  n>=50: m=n-50, unit m>>1, gate f (even) / o (odd).
__device__ __forceinline__ void colmap(int n, int& g, float& scl) {
    if (n < 50) {
        const int r = n >> 1;
        g = ((n & 1) ? 2 : 0) * Hn + r;
        scl = (n & 1) ? SCL_T : SCL_S;
    } else {
        const int m = n - 50, r = m >> 1;
        g = ((m & 1) ? 3 : 1) * Hn + r;
        scl = SCL_S;
    }
}

// =====================  the single fused kernel  =========================
__global__ __launch_bounds__(192, 1)
void lstm_fused2(const float* __restrict__ x, const float* __restrict__ W_ih,
                 const float* __restrict__ W_hh, const float* __restrict__ b_ih,
                 const float* __restrict__ b_hh, const float* __restrict__ W_fc,
                 const float* __restrict__ b_fc, float* __restrict__ out) {
    __shared__ short lB[112 * 72];        // W_ih permuted+scaled bf16
    __shared__ float lbias[112];          // (b_ih+b_hh) permuted+scaled
    __shared__ short xlds[16 * 72];       // x chunk bf16: rows 0-7 = batch A,
                                          //   rows 8-15 = batch B (8 steps ea)
    __shared__ float gbuf[2][2][CH * 100];// [dbuf][batch][step*100+col]
    __shared__ float hbuf[2][16][64];     // [batch][slot][lane] h ring

    const int tid  = threadIdx.x;
    const int wid  = tid >> 6;
    const int lane = tid & 63;
    const int blk  = blockIdx.x;
    const int bA   = 2 * blk;             // two batches per block

    // ---- cooperative staging: W_ih -> lB (bf16, colmap+scale), bias ----
    for (int i = tid; i < 112 * 64; i += 192) {
        const int n = i >> 6, k = i & 63;
        float v = 0.f;
        if (n < Gn) {
            int g; float scl;
            colmap(n, g, scl);
            v = W_ih[(size_t)g * In + k] * scl;
        }
        lB[n * 72 + k] = (short)f2bf(v);
    }
    if (tid < 112) {
        float v = 0.f;
        if (tid < Gn) {
            int g; float scl;
            colmap(tid, g, scl);
            v = (b_ih[g] + b_hh[g]) * scl;
        }
        lbias[tid] = v;
    }
    __syncthreads();

    // ---- per-wave state ----
    float wAv[25], wBv[25];          // wave0: gate weights (batch-invariant!)
    float cA = 0.f, hA = 0.f;        // wave0: batch A state
    float cB = 0.f, hB = 0.f;        // wave0: batch B state
    float sB = 1.f, dB = 0.f;
    int coff = 0;
    float wFC[25];                   // wave1
    float bfc = 0.f;
    float *opA = nullptr, *opB = nullptr;
    short8 bf0[7], bf1[7];           // wave2: resident W_ih fragments
    float biasv[7];
    float4 xr0, xr1, xr2, xr3;       // wave2: x prefetch (next chunk, 2 batches)

    const int quad = lane >> 4;
    const int l16  = lane & 15;
    // wave2 x-load mapping: row 0..15 of xlds; batch = row>>3, brow = row&7
    const int xrow  = lane >> 2;
    const int xc4   = (lane & 3) * 16;
    const float* xsrc0 = x + (size_t)(bA + (xrow >> 3)) * Tn * In
                           + (size_t)(xrow & 7) * In + xc4;

    if (wid == 0) {
        const bool lo = lane < 32;
        const int rr  = min(lane & 31, Hn - 1);
        const float sclA = SCL_S;
        const float sclB = lo ? SCL_T : SCL_S;
        sB = lo ? 2.f : 1.f;
        dB = lo ? -1.f : 0.f;
        const float* rowA = W_hh + (size_t)((lo ? 0 : 1) * Hn + rr) * Hn;
        const float* rowB = W_hh + (size_t)((lo ? 2 : 3) * Hn + rr) * Hn;
#pragma unroll
        for (int j = 0; j < 25; ++j) {
            wAv[j] = rowA[j] * sclA;
            wBv[j] = rowB[j] * sclB;
        }
        coff = 2 * rr + (lo ? 0 : 50);
    } else if (wid == 1) {
#pragma unroll
        for (int j = 0; j < 25; ++j) wFC[j] = W_fc[(size_t)lane * Hn + j];
        bfc = b_fc[lane];
        opA = out + (size_t)bA * Tn * On + lane;
        opB = out + (size_t)(bA + 1) * Tn * On + lane;
    } else {
        // resident B fragments + bias
#pragma unroll
        for (int nt = 0; nt < 7; ++nt) {
            const int col = nt * 16 + l16;
            bf0[nt] = *(const short8*)&lB[col * 72 + 0  + quad * 8];
            bf1[nt] = *(const short8*)&lB[col * 72 + 32 + quad * 8];
            biasv[nt] = lbias[col];
        }
        // load x chunk 0 (both batches, 8 rows each) -> bf16 -> xlds
        const float4 a = *(const float4*)(xsrc0 + 0);
        const float4 d = *(const float4*)(xsrc0 + 4);
        const float4 e = *(const float4*)(xsrc0 + 8);
        const float4 f = *(const float4*)(xsrc0 + 12);
        i32x4 p0, p1;
        p0.x = pk2(a.x, a.y); p0.y = pk2(a.z, a.w);
        p0.z = pk2(d.x, d.y); p0.w = pk2(d.z, d.w);
        p1.x = pk2(e.x, e.y); p1.y = pk2(e.z, e.w);
        p1.z = pk2(f.x, f.y); p1.w = pk2(f.z, f.w);
        *(i32x4*)&xlds[xrow * 72 + xc4 + 0] = p0;
        *(i32x4*)&xlds[xrow * 72 + xc4 + 8] = p1;
    }
    __syncthreads();   // full-drain one-time handoff

    if (wid == 2) {
        // produce chunk 0 -> gbuf[0][batch]; out row = quad*4+i:
        //   batch = quad>>1, step s = (quad&1)*4+i
        const short8 a0 = *(const short8*)&xlds[l16 * 72 + 0  + quad * 8];
        const short8 a1 = *(const short8*)&xlds[l16 * 72 + 32 + quad * 8];
        const int obat = quad >> 1, os = (quad & 1) * 4;
#pragma unroll
        for (int nt = 0; nt < 7; ++nt) {
            f32x4 acc = {biasv[nt], biasv[nt], biasv[nt], biasv[nt]};
            acc = __builtin_amdgcn_mfma_f32_16x16x32_bf16(a0, bf0[nt], acc, 0, 0, 0);
            acc = __builtin_amdgcn_mfma_f32_16x16x32_bf16(a1, bf1[nt], acc, 0, 0, 0);
            const int col = nt * 16 + l16;
            if (col < Gn) {
#pragma unroll
                for (int i = 0; i < 4; ++i)
                    gbuf[0][obat][(os + i) * 100 + col] = acc[i];
            }
        }
        // prefetch x for chunk 1
        const float* xs = xsrc0 + CH * In;
        xr0 = *(const float4*)(xs + 0);
        xr1 = *(const float4*)(xs + 4);
        xr2 = *(const float4*)(xs + 8);
        xr3 = *(const float4*)(xs + 12);
    }
    __syncthreads();   // chunk 0 visible to wave0

    // =========================== main loop ==============================
#pragma unroll 1
    for (int k = 0; k <= NCH; ++k) {
        if (wid == 0) {
            if (k < NCH) {
                const int kb = k & 1;
                float2 gA[CH], gB[CH];
#pragma unroll
                for (int s = 0; s < CH; ++s) {
                    gA[s] = *(const float2*)&gbuf[kb][0][s * 100 + coff];
                    gB[s] = *(const float2*)&gbuf[kb][1][s * 100 + coff];
                }
#pragma unroll
                for (int s = 0; s < CH; ++s) {
                    // two independent chains (batch A, batch B), interleaved
                    float pA0 = gA[s].x, pA1 = 0.f;   // A: gate-A acc
                    float qA0 = gA[s].y, qA1 = 0.f;   // A: gate-B acc
                    float pB0 = gB[s].x, pB1 = 0.f;   // B: gate-A acc
                    float qB0 = gB[s].y, qB1 = 0.f;   // B: gate-B acc
#pragma unroll
                    for (int j = 0; j < 24; j += 2) {
                        const float a0 = bcast(hA, j);
                        const float a1 = bcast(hA, j + 1);
                        const float b0 = bcast(hB, j);
                        const float b1 = bcast(hB, j + 1);
                        pA0 = fmaf(wAv[j],     a0, pA0);
                        qA0 = fmaf(wBv[j],     a0, qA0);
                        pB0 = fmaf(wAv[j],     b0, pB0);
                        qB0 = fmaf(wBv[j],     b0, qB0);
                        pA1 = fmaf(wAv[j + 1], a1, pA1);
                        qA1 = fmaf(wBv[j + 1], a1, qA1);
                        pB1 = fmaf(wAv[j + 1], b1, pB1);
                        qB1 = fmaf(wBv[j + 1], b1, qB1);
                    }
                    {
                        const float a0 = bcast(hA, 24);
                        const float b0 = bcast(hB, 24);
                        pA0 = fmaf(wAv[24], a0, pA0);
                        qA0 = fmaf(wBv[24], a0, qA0);
                        pB0 = fmaf(wAv[24], b0, pB0);
                        qB0 = fmaf(wBv[24], b0, qB0);
                    }
                    const float aAA = pA0 + pA1, aBA = qA0 + qA1;
                    const float aAB = pB0 + pB1, aBB = qB0 + qB1;

                    const float rAA = frcp(1.f + ex2(aAA));  // A: I/F
                    const float rBA = frcp(1.f + ex2(aBA));  // A: sg/O
                    const float rAB = frcp(1.f + ex2(aAB));  // B: I/F
                    const float rBB = frcp(1.f + ex2(aBB));  // B: sg/O
                    const float FgA = xswap(rAA), OgA = xswap(rBA);
                    const float FgB = xswap(rAB), OgB = xswap(rBB);
                    const float acA = fmaf(sB, rBA, dB);
                    const float acB = fmaf(sB, rBB, dB);
                    cA = fmaf(FgA, cA, rAA * acA);
                    cB = fmaf(FgB, cB, rAB * acB);
                    const float r2A = frcp(1.f + ex2(cA * SCL_T));
                    const float r2B = frcp(1.f + ex2(cB * SCL_T));
                    hA = fmaf(OgA + OgA, r2A, -OgA);
                    hB = fmaf(OgB + OgB, r2B, -OgB);

                    const int sl = (k * CH + s) & 15;
                    hbuf[0][sl][lane] = hA;          // junk lanes 25+
                    hbuf[1][sl][lane] = hB;
                }
            }
        } else if (wid == 1) {
            if (k >= 1) {
#pragma unroll
                for (int s = 0; s < CH; ++s) {
                    const int t = (k - 1) * CH + s;
                    const int sl = t & 15;
                    float a0 = bfc, a1 = 0.f, b0 = bfc, b1 = 0.f;
#pragma unroll
                    for (int j = 0; j < 24; j += 2) {
                        a0 = fmaf(hbuf[0][sl][j],     wFC[j],     a0);
                        a1 = fmaf(hbuf[0][sl][j + 1], wFC[j + 1], a1);
                        b0 = fmaf(hbuf[1][sl][j],     wFC[j],     b0);
                        b1 = fmaf(hbuf[1][sl][j + 1], wFC[j + 1], b1);
                    }
                    a0 = fmaf(hbuf[0][sl][24], wFC[24], a0);
                    b0 = fmaf(hbuf[1][sl][24], wFC[24], b0);
                    opA[(size_t)t * On] = a0 + a1;
                    opB[(size_t)t * On] = b0 + b1;
                }
            }
        } else {
            if (k < NCH - 1) {
                // produce chunk k+1 from prefetched regs (vmcnt auto-wait)
                i32x4 p0, p1;
                p0.x = pk2(xr0.x, xr0.y); p0.y = pk2(xr0.z, xr0.w);
                p0.z = pk2(xr1.x, xr1.y); p0.w = pk2(xr1.z, xr1.w);
                p1.x = pk2(xr2.x, xr2.y); p1.y = pk2(xr2.z, xr2.w);
                p1.z = pk2(xr3.x, xr3.y); p1.w = pk2(xr3.z, xr3.w);
                *(i32x4*)&xlds[xrow * 72 + xc4 + 0] = p0;
                *(i32x4*)&xlds[xrow * 72 + xc4 + 8] = p1;
                // prefetch x for chunk k+2
                if (k < NCH - 2) {
                    const float* xs = xsrc0 + (size_t)(k + 2) * (CH * In);
                    xr0 = *(const float4*)(xs + 0);
                    xr1 = *(const float4*)(xs + 4);
                    xr2 = *(const float4*)(xs + 8);
                    xr3 = *(const float4*)(xs + 12);
                }
                asm volatile("s_waitcnt lgkmcnt(0)" ::: "memory");
                const short8 a0 = *(const short8*)&xlds[l16 * 72 + 0  + quad * 8];
                const short8 a1 = *(const short8*)&xlds[l16 * 72 + 32 + quad * 8];
                const int nb = (k + 1) & 1;
                const int obat = quad >> 1, os = (quad & 1) * 4;
#pragma unroll
                for (int nt = 0; nt < 7; ++nt) {
                    f32x4 acc = {biasv[nt], biasv[nt], biasv[nt], biasv[nt]};
                    acc = __builtin_amdgcn_mfma_f32_16x16x32_bf16(a0, bf0[nt], acc, 0, 0, 0);
                    acc = __builtin_amdgcn_mfma_f32_16x16x32_bf16(a1, bf1[nt], acc, 0, 0, 0);
                    const int col = nt * 16 + l16;
                    if (col < Gn) {
#pragma unroll
                        for (int i = 0; i < 4; ++i)
                            gbuf[nb][obat][(os + i) * 100 + col] = acc[i];
                    }
                }
            }
        }
        // raw barrier (R6..R10-proven): drain LDS only; x prefetch in flight
        asm volatile("s_waitcnt lgkmcnt(0)" ::: "memory");
        __builtin_amdgcn_s_barrier();
        asm volatile("" ::: "memory");
    }
}

extern "C" void kernel_launch(void* const* d_in, const int* in_sizes, int n_in,
                              void* d_out, int out_size, void* d_ws, size_t ws_size,
                              hipStream_t stream) {
    const float* x    = (const float*)d_in[0];
    const float* W_ih = (const float*)d_in[1];
    const float* W_hh = (const float*)d_in[2];
    const float* b_ih = (const float*)d_in[3];
    const float* b_hh = (const float*)d_in[4];
    const float* W_fc = (const float*)d_in[5];
    const float* b_fc = (const float*)d_in[6];
    float* out = (float*)d_out;

    lstm_fused2<<<Bn / 2, 192, 0, stream>>>(x, W_ih, W_hh, b_ih, b_hh,
                                            W_fc, b_fc, out);
}

// Round 12
// 303.864 us; speedup vs baseline: 1.6152x; 1.6152x over previous
//
#include <hip/hip_runtime.h>
#include <hip/hip_fp16.h>

// LSTM: B=256, T=1024, I=64, H=25 (4H=100), O=64. fp32 in/out.
//
// R12 theory: R11's 2-chain experiment shows time ∝ instruction count at
//   ~5.5 cy/inst (R10 ~95 inst/550cy; R11 ~190/1000cy), NOT chain-latency
//   bound -> wave0 is issue/serialization-bound. Prime suspect: 25x
//   v_readlane per step, each with VALU-write-SGPR -> VALU-read hazard
//   wait-states. Fix: ZERO readlanes. hbuf (already written per step for
//   the FC wave) doubles as broadcast medium: read h_{t-1} as 7 wave-
//   uniform ds_read_b128 (same-address LDS reads broadcast free), dot via
//   packed v_pk_fma_f32 against pre-packed f32x2 weights (no SGPR data
//   path). ~56 hazard-free inst/step vs ~95. hbuf slot 31 zero-init so
//   t=0 reads h=0; junk-lane h values provably finite so x0 taps safe.
//   Revert to 1 batch/block (R11's 2-batch regressed 2x).
// Structure (validated R9/R10): ONE kernel, 3 waves/block, 1 block/batch:
//   wave0 = recurrence, wave1 = FC + out, wave2 = gate producer (MFMA).
// Carried: gate split across wave halves, exp2 scale folding, (i,g)/(f,o)
//   layout, xswap via permlane32_swap returning b (validated R4), raw
//   s_barrier + lgkmcnt-only drain, __syncthreads one-time handoffs,
//   R10 algebraic forms (swap raw rB; h = fma(2Og, r2, -Og)).

#define Bn 256
#define Tn 1024
#define In 64
#define Hn 25
#define Gn 100
#define On 64
#define CH 16              // steps per chunk
#define NCH (Tn / CH)      // 64 chunks

#define SCL_S -1.44269504089f   // -log2(e)   : sigmoid gates (i,f,o)
#define SCL_T -2.88539008178f   // -2*log2(e) : tanh gate (g)

typedef __attribute__((ext_vector_type(8))) short short8;
typedef __attribute__((ext_vector_type(4))) float f32x4;
typedef __attribute__((ext_vector_type(2))) float f32x2;
typedef __attribute__((ext_vector_type(4))) int i32x4;

__device__ __forceinline__ float frcp(float x) { return __builtin_amdgcn_rcpf(x); }
__device__ __forceinline__ float ex2(float x) {
    float r;
    asm("v_exp_f32 %0, %1\n\ts_nop 1" : "=v"(r) : "v"(x));
    return r;
}
__device__ __forceinline__ float xswap(float x) {
    // returned b's LOW lanes hold the high-half value (validated R4..R11).
    float a = x, b = x;
    asm("s_nop 0\n\tv_permlane32_swap_b32 %0, %1\n\ts_nop 0"
        : "+v"(a), "+v"(b));
    return b;
}
__device__ __forceinline__ unsigned short f2bf(float f) {   // RNE fp32->bf16
    unsigned u = __float_as_uint(f);
    return (unsigned short)((u + 0x7FFFu + ((u >> 16) & 1u)) >> 16);
}
__device__ __forceinline__ int pk2(float lo, float hi) {
    return (int)(((unsigned)f2bf(hi) << 16) | f2bf(lo));
}

// gate column map: n<50: unit n>>1, gate i (even) / g (odd);
//                  n>=50: m=n-50, unit m>>1, gate f (even) / o (odd).
__device__ __forceinline__ void colmap(int n, int& g, float& scl) {
    if (n < 50) {
        const int r = n >> 1;
        g = ((n & 1) ? 2 : 0) * Hn + r;
        scl = (n & 1) ? SCL_T : SCL_S;
    } else {
        const int m = n - 50, r = m >> 1;
        g = ((m & 1) ? 3 : 1) * Hn + r;
        scl = SCL_S;
    }
}

// =====================  the single fused kernel  =========================
__global__ __launch_bounds__(192, 1)
void lstm_fused(const float* __restrict__ x, const float* __restrict__ W_ih,
                const float* __restrict__ W_hh, const float* __restrict__ b_ih,
                const float* __restrict__ b_hh, const float* __restrict__ W_fc,
                const float* __restrict__ b_fc, float* __restrict__ out) {
    __shared__ short lB[112 * 72];       // W_ih permuted+scaled bf16
    __shared__ float lbias[112];         // (b_ih+b_hh) permuted+scaled
    __shared__ short xlds[16 * 72];      // x chunk bf16, MFMA A layout
    __shared__ float gbuf[2][CH * 100];  // gates for 16 steps, dbuf
    __shared__ __align__(16) float hbuf[32][64];  // h ring (2 chunks deep)

    const int tid  = threadIdx.x;
    const int wid  = tid >> 6;
    const int lane = tid & 63;
    const int b    = blockIdx.x;

    // ---- cooperative staging: W_ih -> lB (bf16, colmap+scale), bias ----
    for (int i = tid; i < 112 * 64; i += 192) {
        const int n = i >> 6, k = i & 63;
        float v = 0.f;
        if (n < Gn) {
            int g; float scl;
            colmap(n, g, scl);
            v = W_ih[(size_t)g * In + k] * scl;
        }
        lB[n * 72 + k] = (short)f2bf(v);
    }
    if (tid < 112) {
        float v = 0.f;
        if (tid < Gn) {
            int g; float scl;
            colmap(tid, g, scl);
            v = (b_ih[g] + b_hh[g]) * scl;
        }
        lbias[tid] = v;
    }
    for (int i = tid; i < 32 * 64; i += 192)      // zero h ring (slot 31 is
        ((float*)hbuf)[i] = 0.f;                  // read as h_{-1} at t=0)
    __syncthreads();

    // ---- per-wave state ----
    f32x2 wA2[14], wB2[14];          // wave0: packed gate weights (pad 25..27=0)
    float c = 0.f, h = 0.f;
    float sB = 1.f, dB = 0.f;
    int coff = 0;
    float wFC[25];                   // wave1
    float bfc = 0.f;
    float* op = nullptr;
    short8 bf0[7], bf1[7];           // wave2: resident B fragments
    float biasv[7];
    float4 xr0, xr1, xr2, xr3;       // wave2: x prefetch regs (next chunk)
    const float* xb = x + (size_t)b * Tn * In;

    const int quad = lane >> 4;
    const int l16  = lane & 15;

    if (wid == 0) {
        const bool lo = lane < 32;
        const int rr  = min(lane & 31, Hn - 1);
        const float sclA = SCL_S;
        const float sclB = lo ? SCL_T : SCL_S;
        sB = lo ? 2.f : 1.f;
        dB = lo ? -1.f : 0.f;
        const float* rowA = W_hh + (size_t)((lo ? 0 : 1) * Hn + rr) * Hn;
        const float* rowB = W_hh + (size_t)((lo ? 2 : 3) * Hn + rr) * Hn;
#pragma unroll
        for (int j = 0; j < 14; ++j) {
            const int j0 = 2 * j, j1 = 2 * j + 1;
            wA2[j].x = (j0 < Hn) ? rowA[j0] * sclA : 0.f;
            wA2[j].y = (j1 < Hn) ? rowA[j1] * sclA : 0.f;
            wB2[j].x = (j0 < Hn) ? rowB[j0] * sclB : 0.f;
            wB2[j].y = (j1 < Hn) ? rowB[j1] * sclB : 0.f;
        }
        coff = 2 * rr + (lo ? 0 : 50);
    } else if (wid == 1) {
#pragma unroll
        for (int j = 0; j < 25; ++j) wFC[j] = W_fc[(size_t)lane * Hn + j];
        bfc = b_fc[lane];
        op = out + (size_t)b * Tn * On + lane;
    } else {
        // resident B fragments + bias
#pragma unroll
        for (int nt = 0; nt < 7; ++nt) {
            const int col = nt * 16 + l16;
            bf0[nt] = *(const short8*)&lB[col * 72 + 0  + quad * 8];
            bf1[nt] = *(const short8*)&lB[col * 72 + 32 + quad * 8];
            biasv[nt] = lbias[col];
        }
        // load x chunk 0 (1024 floats; 16/lane) -> bf16 -> xlds
        const int row = lane >> 2, cb = (lane & 3) * 16;
        const float4 a = *(const float4*)(xb + lane * 16 + 0);
        const float4 d = *(const float4*)(xb + lane * 16 + 4);
        const float4 e = *(const float4*)(xb + lane * 16 + 8);
        const float4 f = *(const float4*)(xb + lane * 16 + 12);
        i32x4 p0, p1;
        p0.x = pk2(a.x, a.y); p0.y = pk2(a.z, a.w);
        p0.z = pk2(d.x, d.y); p0.w = pk2(d.z, d.w);
        p1.x = pk2(e.x, e.y); p1.y = pk2(e.z, e.w);
        p1.z = pk2(f.x, f.y); p1.w = pk2(f.z, f.w);
        *(i32x4*)&xlds[row * 72 + cb + 0] = p0;
        *(i32x4*)&xlds[row * 72 + cb + 8] = p1;
    }
    __syncthreads();   // full-drain one-time handoff

    if (wid == 2) {
        // produce chunk 0 into gbuf[0] (all 16 A-rows valid)
        const short8 a0 = *(const short8*)&xlds[l16 * 72 + 0  + quad * 8];
        const short8 a1 = *(const short8*)&xlds[l16 * 72 + 32 + quad * 8];
#pragma unroll
        for (int nt = 0; nt < 7; ++nt) {
            f32x4 acc = {biasv[nt], biasv[nt], biasv[nt], biasv[nt]};
            acc = __builtin_amdgcn_mfma_f32_16x16x32_bf16(a0, bf0[nt], acc, 0, 0, 0);
            acc = __builtin_amdgcn_mfma_f32_16x16x32_bf16(a1, bf1[nt], acc, 0, 0, 0);
            const int col = nt * 16 + l16;
            if (col < Gn) {
#pragma unroll
                for (int i = 0; i < 4; ++i)
                    gbuf[0][(quad * 4 + i) * 100 + col] = acc[i];
            }
        }
        // prefetch x for chunk 1
        const float* xs = xb + 1024;
        xr0 = *(const float4*)(xs + lane * 16 + 0);
        xr1 = *(const float4*)(xs + lane * 16 + 4);
        xr2 = *(const float4*)(xs + lane * 16 + 8);
        xr3 = *(const float4*)(xs + lane * 16 + 12);
    }
    __syncthreads();   // chunk 0 visible to wave0

    // =========================== main loop ==============================
#pragma unroll 1
    for (int k = 0; k <= NCH; ++k) {
        if (wid == 0) {
            if (k < NCH) {
                const int kb = k & 1;
                float2 g[CH];
#pragma unroll
                for (int s = 0; s < CH; ++s)
                    g[s] = *(const float2*)&gbuf[kb][s * 100 + coff];
#pragma unroll
                for (int s = 0; s < CH; ++s) {
                    const int t  = k * CH + s;
                    const int sp = (t - 1) & 31;   // slot of h_{t-1} (31 = zeroed)

                    // wave-uniform h_{t-1}: 7 broadcast ds_read_b128, no
                    // readlanes, no SGPR hazards
                    f32x2 hv[14];
#pragma unroll
                    for (int jj = 0; jj < 7; ++jj) {
                        const float4 r = *(const float4*)&hbuf[sp][4 * jj];
                        hv[2 * jj]     = (f32x2){r.x, r.y};
                        hv[2 * jj + 1] = (f32x2){r.z, r.w};
                    }
                    // packed dot: 28 v_pk_fma_f32, 2 accs per gate
                    f32x2 pa = hv[0] * wA2[0], pb = hv[1] * wA2[1];
                    f32x2 qa = hv[0] * wB2[0], qb = hv[1] * wB2[1];
#pragma unroll
                    for (int j = 2; j < 14; j += 2) {
                        pa += hv[j]     * wA2[j];
                        pb += hv[j + 1] * wA2[j + 1];
                        qa += hv[j]     * wB2[j];
                        qb += hv[j + 1] * wB2[j + 1];
                    }
                    const f32x2 ps = pa + pb, qs = qa + qb;
                    const float aA = g[s].x + (ps.x + ps.y);
                    const float aB = g[s].y + (qs.x + qs.y);

                    const float rA = frcp(1.f + ex2(aA));   // low: I ; high: F
                    const float rB = frcp(1.f + ex2(aB));   // low: sg(2g'); high: O
                    const float Fg = xswap(rA);             // low lanes: F
                    const float Og = xswap(rB);             // low lanes: O
                    const float actB = fmaf(sB, rB, dB);    // low: G = 2rB-1
                    c = fmaf(Fg, c, rA * actB);             // valid lanes 0..24
                    const float r2 = frcp(1.f + ex2(c * SCL_T));
                    h = fmaf(Og + Og, r2, -Og);             // h = O*(2r2-1)

                    hbuf[t & 31][lane] = h;                 // junk lanes 25+
                }
            }
        } else if (wid == 1) {
            if (k >= 1) {
#pragma unroll
                for (int s = 0; s < CH; ++s) {
                    const int t = (k - 1) * CH + s;
                    const int sl = t & 31;
                    float a0 = bfc, a1 = 0.f;
#pragma unroll
                    for (int j = 0; j < 24; j += 2) {
                        a0 = fmaf(hbuf[sl][j],     wFC[j],     a0);
                        a1 = fmaf(hbuf[sl][j + 1], wFC[j + 1], a1);
                    }
                    a0 = fmaf(hbuf[sl][24], wFC[24], a0);
                    op[(size_t)t * On] = a0 + a1;
                }
            }
        } else {
            if (k < NCH - 1) {
                // produce chunk k+1 from prefetched regs (vmcnt auto-wait)
                const int row = lane >> 2, cb = (lane & 3) * 16;
                i32x4 p0, p1;
                p0.x = pk2(xr0.x, xr0.y); p0.y = pk2(xr0.z, xr0.w);
                p0.z = pk2(xr1.x, xr1.y); p0.w = pk2(xr1.z, xr1.w);
                p1.x = pk2(xr2.x, xr2.y); p1.y = pk2(xr2.z, xr2.w);
                p1.z = pk2(xr3.x, xr3.y); p1.w = pk2(xr3.z, xr3.w);
                *(i32x4*)&xlds[row * 72 + cb + 0] = p0;
                *(i32x4*)&xlds[row * 72 + cb + 8] = p1;
                // prefetch x for chunk k+2
                if (k < NCH - 2) {
                    const float* xs = xb + (size_t)(k + 2) * (CH * In);
                    xr0 = *(const float4*)(xs + lane * 16 + 0);
                    xr1 = *(const float4*)(xs + lane * 16 + 4);
                    xr2 = *(const float4*)(xs + lane * 16 + 8);
                    xr3 = *(const float4*)(xs + lane * 16 + 12);
                }
                asm volatile("s_waitcnt lgkmcnt(0)" ::: "memory");
                const short8 a0 = *(const short8*)&xlds[l16 * 72 + 0  + quad * 8];
                const short8 a1 = *(const short8*)&xlds[l16 * 72 + 32 + quad * 8];
                const int nb = (k + 1) & 1;
#pragma unroll
                for (int nt = 0; nt < 7; ++nt) {
                    f32x4 acc = {biasv[nt], biasv[nt], biasv[nt], biasv[nt]};
                    acc = __builtin_amdgcn_mfma_f32_16x16x32_bf16(a0, bf0[nt], acc, 0, 0, 0);
                    acc = __builtin_amdgcn_mfma_f32_16x16x32_bf16(a1, bf1[nt], acc, 0, 0, 0);
                    const int col = nt * 16 + l16;
                    if (col < Gn) {
#pragma unroll
                        for (int i = 0; i < 4; ++i)
                            gbuf[nb][(quad * 4 + i) * 100 + col] = acc[i];
                    }
                }
            }
        }
        // raw barrier (R6..R10-proven): drain LDS only; x prefetch in flight
        asm volatile("s_waitcnt lgkmcnt(0)" ::: "memory");
        __builtin_amdgcn_s_barrier();
        asm volatile("" ::: "memory");
    }
}

extern "C" void kernel_launch(void* const* d_in, const int* in_sizes, int n_in,
                              void* d_out, int out_size, void* d_ws, size_t ws_size,
                              hipStream_t stream) {
    const float* x    = (const float*)d_in[0];
    const float* W_ih = (const float*)d_in[1];
    const float* W_hh = (const float*)d_in[2];
    const float* b_ih = (const float*)d_in[3];
    const float* b_hh = (const float*)d_in[4];
    const float* W_fc = (const float*)d_in[5];
    const float* b_fc = (const float*)d_in[6];
    float* out = (float*)d_out;

    lstm_fused<<<Bn, 192, 0, stream>>>(x, W_ih, W_hh, b_ih, b_hh,
                                       W_fc, b_fc, out);
}